// Round 10
// baseline (1039.361 us; speedup 1.0000x reference)
//
#include <hip/hip_runtime.h>
#include <hip/hip_bf16.h>
#include <stdint.h>

#define B_SZ   512
#define NINST  4
#define D_IN   1024
#define D_OUTD 1024
#define CCOMP  64
#define MRANK  256
#define KTOT   (CCOMP*MRANK)   // 16384

typedef __attribute__((ext_vector_type(4))) float  f32x4;
typedef __attribute__((ext_vector_type(8))) __bf16 bf16x8;
typedef __attribute__((ext_vector_type(4))) __bf16 bf16x4;

__device__ inline void gload_lds16(const __bf16* g, __bf16* l) {
  __builtin_amdgcn_global_load_lds(
      (const __attribute__((address_space(1))) void*)g,
      (__attribute__((address_space(3))) void*)l, 16, 0, 0);
}

// Counted-vmcnt barrier (T4): drain DS + all but the newest 32 VMEM ops
// (the N-operand prefetch loads for step t+2 stay in flight across the
// barrier). FIFO retire: the 4 step-(t+1) DMAs are older -> drained.
#define BAR32() do { \
  asm volatile("s_waitcnt lgkmcnt(0) vmcnt(32)" ::: "memory"); \
  __builtin_amdgcn_sched_barrier(0); \
  __builtin_amdgcn_s_barrier(); \
  __builtin_amdgcn_sched_barrier(0); } while (0)
#define BAR0() do { \
  asm volatile("s_waitcnt lgkmcnt(0) vmcnt(0)" ::: "memory"); \
  __builtin_amdgcn_sched_barrier(0); \
  __builtin_amdgcn_s_barrier(); \
  __builtin_amdgcn_sched_barrier(0); } while (0)

// ---------------------------------------------------------------------------
// Prepass: xbf[i][b][k] = bf16(x[b][i][k]).
// ---------------------------------------------------------------------------
__global__ __launch_bounds__(256)
void xcvt_kernel(const float* __restrict__ x, __bf16* __restrict__ xbf)
{
  const int total = (B_SZ*NINST*D_IN) / 4;
  for (int v = blockIdx.x*256 + threadIdx.x; v < total; v += gridDim.x*256) {
    const int k4 = v & 255;
    const int i  = (v >> 8) & 3;
    const int b  = v >> 10;
    f32x4 f = ((const f32x4*)x)[v];
    bf16x4 h; h[0]=(__bf16)f.x; h[1]=(__bf16)f.y; h[2]=(__bf16)f.z; h[3]=(__bf16)f.w;
    ((bf16x4*)xbf)[((size_t)i*B_SZ + b)*256 + k4] = h;
  }
}

// ---------------------------------------------------------------------------
// Phase 1 (R9 skeleton + T4 counted-vmcnt + 2-deep reg prefetch).
// Tile 128(b) x 128(m), BK=64, 4 waves, 64 steps, 64 KB LDS, 2 blocks/CU.
// ---------------------------------------------------------------------------
__global__ __launch_bounds__(256, 2)
void p1_kernel(const __bf16* __restrict__ xbf, const float* __restrict__ A,
               const int* __restrict__ mask, __bf16* __restrict__ inner)
{
  const int bid = blockIdx.x;
  const int L   = (bid & 7) * 64 + (bid >> 3);   // XCD-chunked, grid 512
  const int bt  = L & 3;
  const int mt  = (L >> 2) & 1;
  const int icg = L >> 3;
  const int ic0 = icg * 4;
  const int i   = ic0 >> 6;
  const int c0  = ic0 & 63;
  const int b0  = bt * 128;
  const int m0  = mt * 128;

  const int tid  = threadIdx.x;
  const int lane = tid & 63;
  const int wid  = tid >> 6;
  const int wr   = wid >> 1;
  const int wc   = wid & 1;

  __shared__ __align__(16) char smem[65536];
  __bf16* Xs = (__bf16*)smem;             // [2][128][64]
  __bf16* As = (__bf16*)(smem + 32768);   // [2][128][64] m-major

  f32x4 acc[4][4];
#pragma unroll
  for (int a_ = 0; a_ < 4; ++a_)
#pragma unroll
    for (int b_ = 0; b_ < 4; ++b_)
      acc[a_][b_] = (f32x4){0.f, 0.f, 0.f, 0.f};

  const __bf16* xbase  = xbf + ((size_t)i * B_SZ + b0) * D_IN;
  const float*  Abase0 = A + (size_t)ic0 * D_IN * MRANK + m0;

  const int bo = tid & 127;
  const int bg = tid >> 7;

  float a0[4][8], a1[4][8];        // two named prefetch banks (rule #20)

  auto stageXs = [&](int buf, int kt) {
#pragma unroll
    for (int q = 0; q < 4; ++q) {
      const int ci  = wid*4 + q;
      const int row = ci*8 + (lane >> 3);
      const int kch = (lane & 7) ^ (row & 7);
      gload_lds16(xbase + (size_t)row * D_IN + (kt & 15)*64 + kch*8,
                  Xs + buf*8192 + ci*512);
    }
  };
  auto loadA = [&](int kt, float (&areg)[4][8]) {
    const float* Ab = Abase0 + (size_t)(kt >> 4) * D_IN * MRANK;
#pragma unroll
    for (int q = 0; q < 4; ++q)
#pragma unroll
      for (int j = 0; j < 8; ++j)
        areg[q][j] = Ab[(size_t)((kt & 15)*64 + (bg*4+q)*8 + j)*MRANK + bo];
  };
  auto writeA = [&](int buf, const float (&areg)[4][8]) {
#pragma unroll
    for (int q = 0; q < 4; ++q) {
      const int oct = bg*4 + q;
      bf16x8 h;
#pragma unroll
      for (int j = 0; j < 8; ++j) h[j] = (__bf16)areg[q][j];
      *(bf16x8*)(As + buf*8192 + bo*64 + ((oct ^ (bo & 7)))*8) = h;
    }
  };
  auto computeStep = [&](int cur) {
#pragma unroll
    for (int kk = 0; kk < 2; ++kk) {
      const int oct = kk*4 + (lane >> 4);
      bf16x8 af[4];
#pragma unroll
      for (int mi = 0; mi < 4; ++mi) {
        const int row = wr*64 + mi*16 + (lane & 15);
        af[mi] = *(const bf16x8*)(Xs + cur*8192 + row*64 + ((oct ^ (row & 7)))*8);
      }
#pragma unroll
      for (int ni = 0; ni < 4; ++ni) {
        const int col = wc*64 + ni*16 + (lane & 15);
        bf16x8 bfr = *(const bf16x8*)(As + cur*8192 + col*64 + ((oct ^ (col & 7)))*8);
#pragma unroll
        for (int mi = 0; mi < 4; ++mi)
          acc[mi][ni] = __builtin_amdgcn_mfma_f32_16x16x32_bf16(af[mi], bfr, acc[mi][ni], 0, 0, 0);
      }
    }
  };
  auto segEpilogue = [&](int kt) {
    const int c = c0 + (kt >> 4);
    __bf16* obase = inner + ((size_t)i * B_SZ + b0) * KTOT + (size_t)c * MRANK + m0;
    float mv[16];
#pragma unroll
    for (int mi = 0; mi < 4; ++mi)
#pragma unroll
      for (int j = 0; j < 4; ++j) {
        const int row = wr*64 + mi*16 + (lane >> 4)*4 + j;
        mv[mi*4+j] = (float)mask[(size_t)(b0 + row) * (NINST*CCOMP) + i*CCOMP + c];
      }
#pragma unroll
    for (int mi = 0; mi < 4; ++mi)
#pragma unroll
      for (int ni = 0; ni < 4; ++ni) {
        const int colL = wc*64 + ni*16 + (lane & 15);
#pragma unroll
        for (int j = 0; j < 4; ++j) {
          const int rowL = wr*64 + mi*16 + (lane >> 4)*4 + j;
          obase[(size_t)rowL * KTOT + colL] = (__bf16)(acc[mi][ni][j] * mv[mi*4+j]);
        }
#pragma unroll
        for (int j = 0; j < 4; ++j) acc[mi][ni][j] = 0.f;
      }
  };

  // prologue: DMA(0) oldest, then A(0)->a0, A(1)->a1; Bs[0] from a0.
  stageXs(0, 0);
  loadA(0, a0); loadA(1, a1);
  writeA(0, a0);                  // compiler emits counted vmcnt (a1 newer)
  BAR32();                        // drains DMA(0); keeps a1 in flight

  int cur = 0;
  for (int t = 0; t < 64; t += 2) {
    // even step t
    if (t+1 < 64) stageXs(cur ^ 1, t+1);
    if (t+2 < 64) loadA(t+2, a0);
    computeStep(cur);
    if (t+1 < 64) writeA(cur ^ 1, a1);
    if (t < 62) BAR32(); else BAR0();
    cur ^= 1;
    // odd step u = t+1
    {
      const int u = t + 1;
      if (u+1 < 64) stageXs(cur ^ 1, u+1);
      if (u+2 < 64) loadA(u+2, a1);
      computeStep(cur);
      if ((u & 15) == 15) segEpilogue(u);
      if (u+1 < 64) writeA(cur ^ 1, a0);
      if (u < 62) BAR32(); else BAR0();
      cur ^= 1;
    }
  }
}

// ---------------------------------------------------------------------------
// Phase 2 (R9 skeleton + T4 counted-vmcnt + 2-deep reg prefetch).
// ---------------------------------------------------------------------------
__global__ __launch_bounds__(256, 2)
void p2_kernel(const __bf16* __restrict__ inner, const float* __restrict__ Bm,
               float* __restrict__ dst, int nks)
{
  const int bid = blockIdx.x;
  const int L   = (bid & 7) * (gridDim.x >> 3) + (bid >> 3);
  const int bt  = L & 3;
  const int nt  = (L >> 2) & 7;
  const int rest = L >> 5;
  const int ks  = rest % nks;
  const int i   = rest / nks;
  const int b0  = bt * 128;
  const int o0  = nt * 128;
  const int NSTEP = (KTOT/64) / nks;
  const int kb0   = ks * NSTEP;

  const int tid  = threadIdx.x;
  const int lane = tid & 63;
  const int wid  = tid >> 6;
  const int wr   = wid >> 1;
  const int wc   = wid & 1;

  __shared__ __align__(16) char smem[65536];
  __bf16* Is = (__bf16*)smem;             // [2][128][64]
  __bf16* Bs = (__bf16*)(smem + 32768);   // [2][128][64] n-major

  f32x4 acc[4][4];
#pragma unroll
  for (int a_ = 0; a_ < 4; ++a_)
#pragma unroll
    for (int b_ = 0; b_ < 4; ++b_)
      acc[a_][b_] = (f32x4){0.f, 0.f, 0.f, 0.f};

  const __bf16* ibase = inner + ((size_t)i * B_SZ + b0) * KTOT;
  const float*  Bbase = Bm + (size_t)i * KTOT * D_OUTD + o0;

  const int bo = tid & 127;
  const int bg = tid >> 7;

  float b0r[4][8], b1r[4][8];

  auto stageIs = [&](int buf, int kt) {
#pragma unroll
    for (int q = 0; q < 4; ++q) {
      const int ci  = wid*4 + q;
      const int row = ci*8 + (lane >> 3);
      const int kch = (lane & 7) ^ (row & 7);
      gload_lds16(ibase + (size_t)row * KTOT + kt*64 + kch*8,
                  Is + buf*8192 + ci*512);
    }
  };
  auto loadB = [&](int kt, float (&breg)[4][8]) {
#pragma unroll
    for (int q = 0; q < 4; ++q)
#pragma unroll
      for (int j = 0; j < 8; ++j)
        breg[q][j] = Bbase[(size_t)(kt*64 + (bg*4+q)*8 + j)*D_OUTD + bo];
  };
  auto writeB = [&](int buf, const float (&breg)[4][8]) {
#pragma unroll
    for (int q = 0; q < 4; ++q) {
      const int oct = bg*4 + q;
      bf16x8 h;
#pragma unroll
      for (int j = 0; j < 8; ++j) h[j] = (__bf16)breg[q][j];
      *(bf16x8*)(Bs + buf*8192 + bo*64 + ((oct ^ (bo & 7)))*8) = h;
    }
  };
  auto computeStep = [&](int cur) {
#pragma unroll
    for (int kk = 0; kk < 2; ++kk) {
      const int oct = kk*4 + (lane >> 4);
      bf16x8 af[4];
#pragma unroll
      for (int mi = 0; mi < 4; ++mi) {
        const int row = wr*64 + mi*16 + (lane & 15);
        af[mi] = *(const bf16x8*)(Is + cur*8192 + row*64 + ((oct ^ (row & 7)))*8);
      }
#pragma unroll
      for (int ni = 0; ni < 4; ++ni) {
        const int col = wc*64 + ni*16 + (lane & 15);
        bf16x8 bfr = *(const bf16x8*)(Bs + cur*8192 + col*64 + ((oct ^ (col & 7)))*8);
#pragma unroll
        for (int mi = 0; mi < 4; ++mi)
          acc[mi][ni] = __builtin_amdgcn_mfma_f32_16x16x32_bf16(af[mi], bfr, acc[mi][ni], 0, 0, 0);
      }
    }
  };

  stageIs(0, kb0);
  loadB(kb0, b0r);
  if (1 < NSTEP) loadB(kb0 + 1, b1r);
  writeB(0, b0r);
  BAR32();

  int cur = 0;
  for (int t = 0; t < NSTEP; t += 2) {
    // even step
    if (t+1 < NSTEP) stageIs(cur ^ 1, kb0 + t + 1);
    if (t+2 < NSTEP) loadB(kb0 + t + 2, b0r);
    computeStep(cur);
    if (t+1 < NSTEP) writeB(cur ^ 1, b1r);
    if (t < NSTEP-2) BAR32(); else BAR0();
    cur ^= 1;
    // odd step
    {
      const int u = t + 1;
      if (u >= NSTEP) break;
      if (u+1 < NSTEP) stageIs(cur ^ 1, kb0 + u + 1);
      if (u+2 < NSTEP) loadB(kb0 + u + 2, b1r);
      computeStep(cur);
      if (u+1 < NSTEP) writeB(cur ^ 1, b0r);
      if (u < NSTEP-2) BAR32(); else BAR0();
      cur ^= 1;
    }
  }

  float* obase = dst + (size_t)ks * ((size_t)B_SZ*NINST*D_OUTD)
               + ((size_t)b0 * NINST + i) * D_OUTD + o0;
#pragma unroll
  for (int mi = 0; mi < 4; ++mi)
#pragma unroll
    for (int ni = 0; ni < 4; ++ni) {
      const int colL = wc*64 + ni*16 + (lane & 15);
#pragma unroll
      for (int j = 0; j < 4; ++j) {
        const int rowL = wr*64 + mi*16 + (lane >> 4)*4 + j;
        obase[(size_t)rowL * (NINST*D_OUTD) + colL] = acc[mi][ni][j];
      }
    }
}

__global__ __launch_bounds__(256)
void reduce_kernel(const float* __restrict__ part, float* __restrict__ out, int nks)
{
  const int total = (B_SZ*NINST*D_OUTD) / 4;
  for (int v = blockIdx.x*256 + threadIdx.x; v < total; v += gridDim.x*256) {
    f32x4 s = ((const f32x4*)part)[v];
    for (int ks = 1; ks < nks; ++ks)
      s += ((const f32x4*)part)[(size_t)ks*total + v];
    ((f32x4*)out)[v] = s;
  }
}

extern "C" void kernel_launch(void* const* d_in, const int* in_sizes, int n_in,
                              void* d_out, int out_size, void* d_ws, size_t ws_size,
                              hipStream_t stream) {
  const float* x    = (const float*)d_in[0];
  const float* A    = (const float*)d_in[1];
  const float* Bm   = (const float*)d_in[2];
  const int*   mask = (const int*)d_in[3];

  const size_t innerB = (size_t)NINST * B_SZ * KTOT * 2;       // 64 MB
  const size_t xbfB   = (size_t)NINST * B_SZ * D_IN * 2;       // 4 MB
  const size_t partB  = (size_t)B_SZ * NINST * D_OUTD * 4;     // 8 MB per split

  char* p = (char*)d_ws;
  __bf16* inner = (__bf16*)p;             p += innerB;
  __bf16* xbf   = (__bf16*)p;             p += xbfB;
  const size_t used = (size_t)(p - (char*)d_ws);

  int nks = 1;
  if      (ws_size >= used + 4*partB) nks = 4;
  else if (ws_size >= used + 2*partB) nks = 2;
  float* part = (nks > 1) ? (float*)p : (float*)d_out;

  xcvt_kernel<<<dim3(1024),  dim3(256), 0, stream>>>(x, xbf);
  p1_kernel<<<dim3(512),     dim3(256), 0, stream>>>(xbf, A, mask, inner);
  p2_kernel<<<dim3(128*nks), dim3(256), 0, stream>>>(inner, Bm, part, nks);
  if (nks > 1)
    reduce_kernel<<<dim3(512), dim3(256), 0, stream>>>(part, (float*)d_out, nks);
}

// Round 11
// 298.217 us; speedup vs baseline: 3.4853x; 3.4853x over previous
//
#include <hip/hip_runtime.h>
#include <hip/hip_bf16.h>
#include <stdint.h>

#define B_SZ   512
#define NINST  4
#define D_IN   1024
#define D_OUTD 1024
#define CCOMP  64
#define MRANK  256
#define KTOT   (CCOMP*MRANK)   // 16384

typedef __attribute__((ext_vector_type(4))) float  f32x4;
typedef __attribute__((ext_vector_type(8))) __bf16 bf16x8;
typedef __attribute__((ext_vector_type(4))) __bf16 bf16x4;

__device__ inline void gload_lds16(const __bf16* g, __bf16* l) {
  __builtin_amdgcn_global_load_lds(
      (const __attribute__((address_space(1))) void*)g,
      (__attribute__((address_space(3))) void*)l, 16, 0, 0);
}

// ---------------------------------------------------------------------------
// Prepass: xbf[i][b][k] = bf16(x[b][i][k]).
// ---------------------------------------------------------------------------
__global__ __launch_bounds__(256)
void xcvt_kernel(const float* __restrict__ x, __bf16* __restrict__ xbf)
{
  const int total = (B_SZ*NINST*D_IN) / 4;
  for (int v = blockIdx.x*256 + threadIdx.x; v < total; v += gridDim.x*256) {
    const int k4 = v & 255;
    const int i  = (v >> 8) & 3;
    const int b  = v >> 10;
    f32x4 f = ((const f32x4*)x)[v];
    bf16x4 h; h[0]=(__bf16)f.x; h[1]=(__bf16)f.y; h[2]=(__bf16)f.z; h[3]=(__bf16)f.w;
    ((bf16x4*)xbf)[((size_t)i*B_SZ + b)*256 + k4] = h;
  }
}

// ---------------------------------------------------------------------------
// Phase 1, reshaped: tile 256(b) x 128(m), BK=32, 512 thr = 8 waves (4x2),
// wave tile 64x64.  Halves A's block-sharing multiplicity (2 blocks/A-byte)
// and cuts scalar A-loads to 8/thread/step (R3's best-p1 had 16; R9 had 32).
// Seg-batch 2 c's -> 64 steps, dbuf, LDS 48 KB, grid 512 (1 round, 2/CU).
// Skeleton = proven R9 (plain __syncthreads, 1 barrier/step).
// ---------------------------------------------------------------------------
__global__ __launch_bounds__(512, 2)
void p1_kernel(const __bf16* __restrict__ xbf, const float* __restrict__ A,
               const int* __restrict__ mask, __bf16* __restrict__ inner)
{
  const int bid = blockIdx.x;
  const int L   = (bid & 7) * 64 + (bid >> 3);   // XCD-chunked, grid 512
  const int bt  = L & 1;
  const int mt  = (L >> 1) & 1;
  const int icg = L >> 2;          // 0..127
  const int ic0 = icg * 2;         // 2 consecutive c's, never straddles i
  const int i   = ic0 >> 6;
  const int c0  = ic0 & 63;
  const int b0  = bt * 256;
  const int m0  = mt * 128;

  const int tid  = threadIdx.x;
  const int lane = tid & 63;
  const int wid  = tid >> 6;       // 0..7
  const int wr   = wid >> 1;       // 0..3 : 64-row strip
  const int wc   = wid & 1;        // 0..1 : 64-col strip

  __shared__ __align__(16) char smem[49152];
  __bf16* Xs = (__bf16*)smem;             // [2][256][32] bf16, 32 KB
  __bf16* As = (__bf16*)(smem + 32768);   // [2][128][32] m-major, 16 KB

  f32x4 acc[4][4];
#pragma unroll
  for (int a_ = 0; a_ < 4; ++a_)
#pragma unroll
    for (int b_ = 0; b_ < 4; ++b_)
      acc[a_][b_] = (f32x4){0.f, 0.f, 0.f, 0.f};

  const __bf16* xbase = xbf + ((size_t)i * B_SZ + b0) * D_IN;

  const int am = tid & 127;        // A column m (within 128)
  const int ag = tid >> 7;         // 0..3 -> one k-octet each

  float areg[8];

  auto stageXs = [&](int buf, int kt) {
#pragma unroll
    for (int q = 0; q < 2; ++q) {
      const int ci  = wid*2 + q;                 // 0..15, wave-uniform
      const int row = ci*16 + (lane >> 2);       // 16 rows per DMA unit
      const int kch = (lane & 3) ^ (row & 3);    // pre-swizzled source
      gload_lds16(xbase + (size_t)row * D_IN + (kt & 31)*32 + kch*8,
                  Xs + buf*8192 + ci*512);
    }
  };
  auto loadA = [&](int kt) {
    const float* Ab = A + (size_t)(ic0 + (kt >> 5)) * D_IN * MRANK + m0;
#pragma unroll
    for (int j = 0; j < 8; ++j)
      areg[j] = Ab[(size_t)((kt & 31)*32 + ag*8 + j)*MRANK + am];
  };
  auto writeA = [&](int buf) {
    bf16x8 h;
#pragma unroll
    for (int j = 0; j < 8; ++j) h[j] = (__bf16)areg[j];
    *(bf16x8*)(As + buf*4096 + am*32 + ((ag ^ (am & 3)))*8) = h;
  };
  auto computeStep = [&](int cur) {
    const int oct = lane >> 4;     // K=32 -> 4 octets, one per lane-quad
    bf16x8 af[4];
#pragma unroll
    for (int mi = 0; mi < 4; ++mi) {
      const int row = wr*64 + mi*16 + (lane & 15);
      af[mi] = *(const bf16x8*)(Xs + cur*8192 + row*32 + ((oct ^ (row & 3)))*8);
    }
#pragma unroll
    for (int ni = 0; ni < 4; ++ni) {
      const int col = wc*64 + ni*16 + (lane & 15);
      bf16x8 bfr = *(const bf16x8*)(As + cur*4096 + col*32 + ((oct ^ (col & 3)))*8);
#pragma unroll
      for (int mi = 0; mi < 4; ++mi)
        acc[mi][ni] = __builtin_amdgcn_mfma_f32_16x16x32_bf16(af[mi], bfr, acc[mi][ni], 0, 0, 0);
    }
  };
  auto segEpilogue = [&](int kt) {
    const int c = c0 + (kt >> 5);
    __bf16* obase = inner + ((size_t)i * B_SZ + b0) * KTOT + (size_t)c * MRANK + m0;
    float mv[16];
#pragma unroll
    for (int mi = 0; mi < 4; ++mi)
#pragma unroll
      for (int j = 0; j < 4; ++j) {
        const int row = wr*64 + mi*16 + (lane >> 4)*4 + j;
        mv[mi*4+j] = (float)mask[(size_t)(b0 + row) * (NINST*CCOMP) + i*CCOMP + c];
      }
#pragma unroll
    for (int mi = 0; mi < 4; ++mi)
#pragma unroll
      for (int ni = 0; ni < 4; ++ni) {
        const int colL = wc*64 + ni*16 + (lane & 15);
#pragma unroll
        for (int j = 0; j < 4; ++j) {
          const int rowL = wr*64 + mi*16 + (lane >> 4)*4 + j;
          obase[(size_t)rowL * KTOT + colL] = (__bf16)(acc[mi][ni][j] * mv[mi*4+j]);
        }
#pragma unroll
        for (int j = 0; j < 4; ++j) acc[mi][ni][j] = 0.f;
      }
  };

  stageXs(0, 0); loadA(0); writeA(0);
  __syncthreads();

  int cur = 0;
  for (int kt = 0; kt < 64; ++kt) {
    if (kt+1 < 64) { stageXs(cur ^ 1, kt+1); loadA(kt+1); }
    computeStep(cur);
    if ((kt & 31) == 31) segEpilogue(kt);
    if (kt+1 < 64) writeA(cur ^ 1);
    __syncthreads();
    cur ^= 1;
  }
}

// ---------------------------------------------------------------------------
// Phase 2 (exact R9/R7 version, measured ~92 us): part[ks][b][i][o] =
// sum_{K slice} inner . Bflat.  128x128, BK=64, 4 waves, 64 KB LDS, 2/CU.
// ---------------------------------------------------------------------------
__global__ __launch_bounds__(256, 2)
void p2_kernel(const __bf16* __restrict__ inner, const float* __restrict__ Bm,
               float* __restrict__ dst, int nks)
{
  const int bid = blockIdx.x;
  const int L   = (bid & 7) * (gridDim.x >> 3) + (bid >> 3);
  const int bt  = L & 3;
  const int nt  = (L >> 2) & 7;
  const int rest = L >> 5;         // i*nks + ks
  const int ks  = rest % nks;
  const int i   = rest / nks;
  const int b0  = bt * 128;
  const int o0  = nt * 128;
  const int NSTEP = (KTOT/64) / nks;
  const int kb0   = ks * NSTEP;

  const int tid  = threadIdx.x;
  const int lane = tid & 63;
  const int wid  = tid >> 6;
  const int wr   = wid >> 1;
  const int wc   = wid & 1;

  __shared__ __align__(16) char smem[65536];
  __bf16* Is = (__bf16*)smem;             // [2][128][64]
  __bf16* Bs = (__bf16*)(smem + 32768);   // [2][128][64] n-major

  f32x4 acc[4][4];
#pragma unroll
  for (int a_ = 0; a_ < 4; ++a_)
#pragma unroll
    for (int b_ = 0; b_ < 4; ++b_)
      acc[a_][b_] = (f32x4){0.f, 0.f, 0.f, 0.f};

  const __bf16* ibase = inner + ((size_t)i * B_SZ + b0) * KTOT;
  const float*  Bbase = Bm + (size_t)i * KTOT * D_OUTD + o0;

  const int bo = tid & 127;
  const int bg = tid >> 7;

  float breg[4][8];

  auto stageIs = [&](int buf, int kt) {
#pragma unroll
    for (int q = 0; q < 4; ++q) {
      const int ci  = wid*4 + q;
      const int row = ci*8 + (lane >> 3);
      const int kch = (lane & 7) ^ (row & 7);
      gload_lds16(ibase + (size_t)row * KTOT + kt*64 + kch*8,
                  Is + buf*8192 + ci*512);
    }
  };
  auto loadB = [&](int kt) {
#pragma unroll
    for (int q = 0; q < 4; ++q)
#pragma unroll
      for (int j = 0; j < 8; ++j)
        breg[q][j] = Bbase[(size_t)(kt*64 + (bg*4+q)*8 + j)*D_OUTD + bo];
  };
  auto writeB = [&](int buf) {
#pragma unroll
    for (int q = 0; q < 4; ++q) {
      const int oct = bg*4 + q;
      bf16x8 h;
#pragma unroll
      for (int j = 0; j < 8; ++j) h[j] = (__bf16)breg[q][j];
      *(bf16x8*)(Bs + buf*8192 + bo*64 + ((oct ^ (bo & 7)))*8) = h;
    }
  };

  stageIs(0, kb0); loadB(kb0); writeB(0);
  __syncthreads();

  int cur = 0;
  for (int t = 0; t < NSTEP; ++t) {
    if (t+1 < NSTEP) { stageIs(cur ^ 1, kb0 + t + 1); loadB(kb0 + t + 1); }
#pragma unroll
    for (int kk = 0; kk < 2; ++kk) {
      const int oct = kk*4 + (lane >> 4);
      bf16x8 af[4];
#pragma unroll
      for (int mi = 0; mi < 4; ++mi) {
        const int row = wr*64 + mi*16 + (lane & 15);
        af[mi] = *(const bf16x8*)(Is + cur*8192 + row*64 + ((oct ^ (row & 7)))*8);
      }
#pragma unroll
      for (int ni = 0; ni < 4; ++ni) {
        const int col = wc*64 + ni*16 + (lane & 15);
        bf16x8 bfr = *(const bf16x8*)(Bs + cur*8192 + col*64 + ((oct ^ (col & 7)))*8);
#pragma unroll
        for (int mi = 0; mi < 4; ++mi)
          acc[mi][ni] = __builtin_amdgcn_mfma_f32_16x16x32_bf16(af[mi], bfr, acc[mi][ni], 0, 0, 0);
      }
    }
    if (t+1 < NSTEP) writeB(cur ^ 1);
    __syncthreads();
    cur ^= 1;
  }

  float* obase = dst + (size_t)ks * ((size_t)B_SZ*NINST*D_OUTD)
               + ((size_t)b0 * NINST + i) * D_OUTD + o0;
#pragma unroll
  for (int mi = 0; mi < 4; ++mi)
#pragma unroll
    for (int ni = 0; ni < 4; ++ni) {
      const int colL = wc*64 + ni*16 + (lane & 15);
#pragma unroll
      for (int j = 0; j < 4; ++j) {
        const int rowL = wr*64 + mi*16 + (lane >> 4)*4 + j;
        obase[(size_t)rowL * (NINST*D_OUTD) + colL] = acc[mi][ni][j];
      }
    }
}

__global__ __launch_bounds__(256)
void reduce_kernel(const float* __restrict__ part, float* __restrict__ out, int nks)
{
  const int total = (B_SZ*NINST*D_OUTD) / 4;
  for (int v = blockIdx.x*256 + threadIdx.x; v < total; v += gridDim.x*256) {
    f32x4 s = ((const f32x4*)part)[v];
    for (int ks = 1; ks < nks; ++ks)
      s += ((const f32x4*)part)[(size_t)ks*total + v];
    ((f32x4*)out)[v] = s;
  }
}

extern "C" void kernel_launch(void* const* d_in, const int* in_sizes, int n_in,
                              void* d_out, int out_size, void* d_ws, size_t ws_size,
                              hipStream_t stream) {
  const float* x    = (const float*)d_in[0];
  const float* A    = (const float*)d_in[1];
  const float* Bm   = (const float*)d_in[2];
  const int*   mask = (const int*)d_in[3];

  const size_t innerB = (size_t)NINST * B_SZ * KTOT * 2;       // 64 MB
  const size_t xbfB   = (size_t)NINST * B_SZ * D_IN * 2;       // 4 MB
  const size_t partB  = (size_t)B_SZ * NINST * D_OUTD * 4;     // 8 MB per split

  char* p = (char*)d_ws;
  __bf16* inner = (__bf16*)p;             p += innerB;
  __bf16* xbf   = (__bf16*)p;             p += xbfB;
  const size_t used = (size_t)(p - (char*)d_ws);

  int nks = 1;
  if      (ws_size >= used + 4*partB) nks = 4;
  else if (ws_size >= used + 2*partB) nks = 2;
  float* part = (nks > 1) ? (float*)p : (float*)d_out;

  xcvt_kernel<<<dim3(1024),  dim3(256), 0, stream>>>(x, xbf);
  p1_kernel<<<dim3(512),     dim3(512), 0, stream>>>(xbf, A, mask, inner);
  p2_kernel<<<dim3(128*nks), dim3(256), 0, stream>>>(inner, Bm, part, nks);
  if (nks > 1)
    reduce_kernel<<<dim3(512), dim3(256), 0, stream>>>(part, (float*)d_out, nks);
}